// Round 1
// baseline (6893.928 us; speedup 1.0000x reference)
//
#include <hip/hip_runtime.h>
#include <cstddef>

#define Bz 8
#define Nn 16384
#define MD 256
#define Ff 32
#define Hh 4
#define Gg 32
#define G3v 32768
#define CKV 140

// ---------------- Pass 1: kv = W·X (per batch), fused BN statistics ----------------
// Grid: 2048 blocks (8 batches x 256 n-chunks of 64), 256 threads.
// Each thread owns channels c = tx + 32*cg (cg=0..4) x 8 columns (n = n0 + ty*8 + j).
__global__ __launch_bounds__(256) void gemm_stats_kernel(
    const float* __restrict__ X, const float* __restrict__ W,
    float* __restrict__ vals, float* __restrict__ keys,
    float* __restrict__ gsum, float* __restrict__ gsq)
{
    __shared__ float Xs[64][64];     // [k][n]
    __shared__ float Ws[64][161];    // [k][c], stride 161 => conflict-free writes, cols 140..159 zero pad
    __shared__ float red[280];

    const int bid = blockIdx.x;
    const int b   = bid >> 8;
    const int n0  = (bid & 255) << 6;
    const int t   = threadIdx.x;
    const int tx  = t & 31;
    const int ty  = t >> 5;

    float acc[5][8];
    #pragma unroll
    for (int i = 0; i < 5; ++i)
        #pragma unroll
        for (int j = 0; j < 8; ++j) acc[i][j] = 0.f;

    for (int k0 = 0; k0 < MD; k0 += 64) {
        // load X tile 64x64 (float4, coalesced)
        {
            const int r  = t >> 4;
            const int c4 = (t & 15) << 2;
            #pragma unroll
            for (int i = 0; i < 4; ++i) {
                const int k = r + i * 16;
                const float4 v = *reinterpret_cast<const float4*>(
                    X + (size_t)(b * MD + k0 + k) * Nn + n0 + c4);
                *reinterpret_cast<float4*>(&Xs[k][c4]) = v;
            }
        }
        // load W tile transposed: Ws[k][c] = W[c][k0+k]; zero-fill pad columns
        for (int idx = t; idx < 64 * 160; idx += 256) {
            const int c = idx >> 6;
            const int k = idx & 63;
            Ws[k][c] = (c < CKV) ? W[c * MD + k0 + k] : 0.f;
        }
        __syncthreads();

        for (int k = 0; k < 64; ++k) {
            float xv[8];
            *reinterpret_cast<float4*>(&xv[0]) = *reinterpret_cast<const float4*>(&Xs[k][ty * 8]);
            *reinterpret_cast<float4*>(&xv[4]) = *reinterpret_cast<const float4*>(&Xs[k][ty * 8 + 4]);
            const float w0 = Ws[k][tx];
            const float w1 = Ws[k][tx + 32];
            const float w2 = Ws[k][tx + 64];
            const float w3 = Ws[k][tx + 96];
            const float w4 = Ws[k][tx + 128];   // zero for c>=140 (padded)
            #pragma unroll
            for (int j = 0; j < 8; ++j) {
                acc[0][j] = fmaf(w0, xv[j], acc[0][j]);
                acc[1][j] = fmaf(w1, xv[j], acc[1][j]);
                acc[2][j] = fmaf(w2, xv[j], acc[2][j]);
                acc[3][j] = fmaf(w3, xv[j], acc[3][j]);
                acc[4][j] = fmaf(w4, xv[j], acc[4][j]);
            }
        }
        __syncthreads();
    }

    // ---- write raw kv: keys -> (B,H,3,N), vals -> (B,H,N,F) ----
    const int nb = n0 + ty * 8;
    #pragma unroll
    for (int cg = 0; cg < 5; ++cg) {
        const int c = tx + 32 * cg;
        if (c >= CKV) continue;
        if (c < 12) {
            const int hh = c / 3, kk = c - (c / 3) * 3;
            float* dst = keys + (size_t)((b * Hh + hh) * 3 + kk) * Nn + nb;
            #pragma unroll
            for (int j = 0; j < 8; ++j) dst[j] = acc[cg][j];
        } else {
            const int cv = c - 12;
            const int hh = cv >> 5, f = cv & 31;
            float* dst = vals + ((size_t)(b * Hh + hh) * Nn + nb) * Ff + f;
            #pragma unroll
            for (int j = 0; j < 8; ++j) dst[(size_t)j * Ff] = acc[cg][j];
        }
    }

    // ---- BN statistics: LDS reduce, then per-channel global atomics ----
    red[t] = 0.f;
    if (t < 24) red[256 + t] = 0.f;
    __syncthreads();
    #pragma unroll
    for (int cg = 0; cg < 5; ++cg) {
        const int c = tx + 32 * cg;
        if (c >= CKV) continue;
        float s = 0.f, q = 0.f;
        #pragma unroll
        for (int j = 0; j < 8; ++j) { s += acc[cg][j]; q = fmaf(acc[cg][j], acc[cg][j], q); }
        atomicAdd(&red[c], s);
        atomicAdd(&red[140 + c], q);
    }
    __syncthreads();
    if (t < CKV) {
        atomicAdd(&gsum[t], red[t]);
        atomicAdd(&gsq[t],  red[140 + t]);
    }
}

// ---------------- Pass 2: finalize BN affine params ----------------
__global__ void finalize_kernel(const float* __restrict__ gsum, const float* __restrict__ gsq,
                                const float* __restrict__ kg, const float* __restrict__ kb,
                                const float* __restrict__ vg, const float* __restrict__ vb,
                                float* __restrict__ scale, float* __restrict__ shift)
{
    const int c = threadIdx.x;
    if (c < CKV) {
        const float inv = 1.f / (float)(Bz * Nn);
        const float m = gsum[c] * inv;
        const float v = fmaf(-m, m, gsq[c] * inv);
        float ga, be;
        if (c < 12) { ga = kg[c]; be = kb[c]; }
        else        { ga = vg[c - 12]; be = vb[c - 12]; }
        const float sc = ga * rsqrtf(v + 1e-5f);
        scale[c] = sc;
        shift[c] = fmaf(-m, sc, be);
    }
}

// ---------------- Pass 3: transform + trilinear splat scatter ----------------
// Grid: 1024 blocks = 32 (b,h) groups x 32 chunks; 256 threads, 2 points/thread.
__global__ __launch_bounds__(256) void scatter_kernel(
    const float* __restrict__ vals, const float* __restrict__ keys,
    const float* __restrict__ orig, const float* __restrict__ Rm,
    const float* __restrict__ tv, const float* __restrict__ scale,
    const float* __restrict__ shift, float* __restrict__ out)
{
    const int bid   = blockIdx.x;
    const int g     = bid >> 5;    // (b*H + h)
    const int chunk = bid & 31;
    const int b     = g >> 2;
    const int h     = g & 3;

    __shared__ float sc[32], sh[32], sR[9], st3[3], ksc[3], ksh[3];
    const int t = threadIdx.x;
    if (t < 32)               { sc[t] = scale[12 + h * 32 + t]; sh[t] = shift[12 + h * 32 + t]; }
    else if (t < 41)          { sR[t - 32]  = Rm[h * 9 + (t - 32)]; }
    else if (t < 44)          { st3[t - 41] = tv[h * 3 + (t - 41)]; }
    else if (t < 47)          { ksc[t - 44] = scale[h * 3 + (t - 44)];
                                ksh[t - 44] = shift[h * 3 + (t - 44)]; }
    __syncthreads();

    float* const og = out + ((size_t)g << 20);   // g * F * G3

    #pragma unroll
    for (int pp = 0; pp < 2; ++pp) {
        const int n = (chunk << 9) + (pp << 8) + t;

        const float k0 = fmaf(keys[(size_t)(g * 3 + 0) * Nn + n], ksc[0], ksh[0]);
        const float k1 = fmaf(keys[(size_t)(g * 3 + 1) * Nn + n], ksc[1], ksh[1]);
        const float k2 = fmaf(keys[(size_t)(g * 3 + 2) * Nn + n], ksc[2], ksh[2]);
        const float p0 = orig[(size_t)(b * 3 + 0) * Nn + n] + k0;
        const float p1 = orig[(size_t)(b * 3 + 1) * Nn + n] + k1;
        const float p2 = orig[(size_t)(b * 3 + 2) * Nn + n] + k2;

        int   idx[3];
        float loc[3];
        #pragma unroll
        for (int i = 0; i < 3; ++i) {
            const float tk = fmaf(sR[i*3+0], p0, fmaf(sR[i*3+1], p1, fmaf(sR[i*3+2], p2, st3[i])));
            const float la = tanhf(tk);
            const float po = (la + 1.f) * 15.5f;
            float fi = floorf(po);
            fi = fminf(fmaxf(fi, 0.f), 30.f);
            idx[i] = (int)fi;
            loc[i] = po - fi;
        }
        const int cell = (idx[0] * Gg + idx[1]) * Gg + idx[2];

        float v[32];
        const float4* vp = reinterpret_cast<const float4*>(vals + ((size_t)g * Nn + n) * Ff);
        #pragma unroll
        for (int q = 0; q < 8; ++q) {
            const float4 x = vp[q];
            v[4*q+0] = fmaf(x.x, sc[4*q+0], sh[4*q+0]);
            v[4*q+1] = fmaf(x.y, sc[4*q+1], sh[4*q+1]);
            v[4*q+2] = fmaf(x.z, sc[4*q+2], sh[4*q+2]);
            v[4*q+3] = fmaf(x.w, sc[4*q+3], sh[4*q+3]);
        }

        const float wx1 = loc[0], wx0 = 1.f - loc[0];
        const float wy1 = loc[1], wy0 = 1.f - loc[1];
        const float wz1 = loc[2], wz0 = 1.f - loc[2];
        const float cw[8] = { wx0*wy0*wz0, wx0*wy0*wz1, wx0*wy1*wz0, wx0*wy1*wz1,
                              wx1*wy0*wz0, wx1*wy0*wz1, wx1*wy1*wz0, wx1*wy1*wz1 };
        const int  co[8] = { 0, 1, 32, 33, 1024, 1025, 1056, 1057 };

        #pragma unroll
        for (int f = 0; f < 32; ++f) {
            float* const pf = og + (size_t)f * G3v + cell;
            const float vf = v[f];
            #pragma unroll
            for (int c8 = 0; c8 < 8; ++c8) {
                atomicAdd(pf + co[c8], cw[c8] * vf);
            }
        }
    }
}

extern "C" void kernel_launch(void* const* d_in, const int* in_sizes, int n_in,
                              void* d_out, int out_size, void* d_ws, size_t ws_size,
                              hipStream_t stream)
{
    const float* X    = (const float*)d_in[0];
    const float* orig = (const float*)d_in[1];
    const float* W    = (const float*)d_in[2];
    const float* kg   = (const float*)d_in[3];
    const float* kb   = (const float*)d_in[4];
    const float* vg   = (const float*)d_in[5];
    const float* vb   = (const float*)d_in[6];
    const float* Rm   = (const float*)d_in[7];
    const float* tv   = (const float*)d_in[8];
    float* out = (float*)d_out;
    float* ws  = (float*)d_ws;

    // workspace layout (floats): vals 16,777,216 | keys 1,572,864 | sum 140 | sq 140 | scale 140 | shift 140
    float* vals  = ws;
    float* keys  = ws + 16777216;
    float* gsum  = ws + 18350080;
    float* gsq   = gsum + 140;
    float* scale = gsum + 280;
    float* shift = scale + 140;

    hipMemsetAsync(gsum, 0, 280 * sizeof(float), stream);
    hipMemsetAsync(out, 0, (size_t)out_size * sizeof(float), stream);

    gemm_stats_kernel<<<2048, 256, 0, stream>>>(X, W, vals, keys, gsum, gsq);
    finalize_kernel<<<1, 256, 0, stream>>>(gsum, gsq, kg, kb, vg, vb, scale, shift);
    scatter_kernel<<<1024, 256, 0, stream>>>(vals, keys, orig, Rm, tv, scale, shift, out);
}

// Round 2
// 804.432 us; speedup vs baseline: 8.5699x; 8.5699x over previous
//
#include <hip/hip_runtime.h>
#include <cstddef>

#define Bz 8
#define Nn 16384
#define MD 256
#define Ff 32
#define Hh 4
#define Gg 32
#define G3v 32768
#define CKV 140

// ---------------- Pass 1: kv = W·X (per batch), fused BN statistics ----------------
__global__ __launch_bounds__(256) void gemm_stats_kernel(
    const float* __restrict__ X, const float* __restrict__ W,
    float* __restrict__ vals, float* __restrict__ keys,
    float* __restrict__ gsum, float* __restrict__ gsq)
{
    __shared__ float Xs[64][64];     // [k][n]
    __shared__ float Ws[64][161];    // [k][c], stride 161; cols 140..159 zero pad
    __shared__ float red[280];

    const int bid = blockIdx.x;
    const int b   = bid >> 8;
    const int n0  = (bid & 255) << 6;
    const int t   = threadIdx.x;
    const int tx  = t & 31;
    const int ty  = t >> 5;

    float acc[5][8];
    #pragma unroll
    for (int i = 0; i < 5; ++i)
        #pragma unroll
        for (int j = 0; j < 8; ++j) acc[i][j] = 0.f;

    for (int k0 = 0; k0 < MD; k0 += 64) {
        {
            const int r  = t >> 4;
            const int c4 = (t & 15) << 2;
            #pragma unroll
            for (int i = 0; i < 4; ++i) {
                const int k = r + i * 16;
                const float4 v = *reinterpret_cast<const float4*>(
                    X + (size_t)(b * MD + k0 + k) * Nn + n0 + c4);
                *reinterpret_cast<float4*>(&Xs[k][c4]) = v;
            }
        }
        for (int idx = t; idx < 64 * 160; idx += 256) {
            const int c = idx >> 6;
            const int k = idx & 63;
            Ws[k][c] = (c < CKV) ? W[c * MD + k0 + k] : 0.f;
        }
        __syncthreads();

        for (int k = 0; k < 64; ++k) {
            float xv[8];
            *reinterpret_cast<float4*>(&xv[0]) = *reinterpret_cast<const float4*>(&Xs[k][ty * 8]);
            *reinterpret_cast<float4*>(&xv[4]) = *reinterpret_cast<const float4*>(&Xs[k][ty * 8 + 4]);
            const float w0 = Ws[k][tx];
            const float w1 = Ws[k][tx + 32];
            const float w2 = Ws[k][tx + 64];
            const float w3 = Ws[k][tx + 96];
            const float w4 = Ws[k][tx + 128];
            #pragma unroll
            for (int j = 0; j < 8; ++j) {
                acc[0][j] = fmaf(w0, xv[j], acc[0][j]);
                acc[1][j] = fmaf(w1, xv[j], acc[1][j]);
                acc[2][j] = fmaf(w2, xv[j], acc[2][j]);
                acc[3][j] = fmaf(w3, xv[j], acc[3][j]);
                acc[4][j] = fmaf(w4, xv[j], acc[4][j]);
            }
        }
        __syncthreads();
    }

    const int nb = n0 + ty * 8;
    #pragma unroll
    for (int cg = 0; cg < 5; ++cg) {
        const int c = tx + 32 * cg;
        if (c >= CKV) continue;
        if (c < 12) {
            const int hh = c / 3, kk = c - (c / 3) * 3;
            float* dst = keys + (size_t)((b * Hh + hh) * 3 + kk) * Nn + nb;
            #pragma unroll
            for (int j = 0; j < 8; ++j) dst[j] = acc[cg][j];
        } else {
            const int cv = c - 12;
            const int hh = cv >> 5, f = cv & 31;
            float* dst = vals + ((size_t)(b * Hh + hh) * Nn + nb) * Ff + f;
            #pragma unroll
            for (int j = 0; j < 8; ++j) dst[(size_t)j * Ff] = acc[cg][j];
        }
    }

    red[t] = 0.f;
    if (t < 24) red[256 + t] = 0.f;
    __syncthreads();
    #pragma unroll
    for (int cg = 0; cg < 5; ++cg) {
        const int c = tx + 32 * cg;
        if (c >= CKV) continue;
        float s = 0.f, q = 0.f;
        #pragma unroll
        for (int j = 0; j < 8; ++j) { s += acc[cg][j]; q = fmaf(acc[cg][j], acc[cg][j], q); }
        atomicAdd(&red[c], s);
        atomicAdd(&red[140 + c], q);
    }
    __syncthreads();
    if (t < CKV) {
        atomicAdd(&gsum[t], red[t]);
        atomicAdd(&gsq[t],  red[140 + t]);
    }
}

// ---------------- Pass 2: finalize BN affine params ----------------
__global__ void finalize_kernel(const float* __restrict__ gsum, const float* __restrict__ gsq,
                                const float* __restrict__ kg, const float* __restrict__ kb,
                                const float* __restrict__ vg, const float* __restrict__ vb,
                                float* __restrict__ scale, float* __restrict__ shift)
{
    const int c = threadIdx.x;
    if (c < CKV) {
        const float inv = 1.f / (float)(Bz * Nn);
        const float m = gsum[c] * inv;
        const float v = fmaf(-m, m, gsq[c] * inv);
        float ga, be;
        if (c < 12) { ga = kg[c]; be = kb[c]; }
        else        { ga = vg[c - 12]; be = vb[c - 12]; }
        const float sc = ga * rsqrtf(v + 1e-5f);
        scale[c] = sc;
        shift[c] = fmaf(-m, sc, be);
    }
}

// ---------------- Pass 3 (new): f-contiguous coalesced-atomic scatter ----------------
// tmp layout: [g][cell][f] (f contiguous). 32-lane group = 32 f's of one point.
// Grid: 2048 blocks = 32 g x 64 chunks of 256 points; block 256 = 8 groups x 32 lanes.
__global__ __launch_bounds__(256) void scatter_cf_kernel(
    const float* __restrict__ vals, const float* __restrict__ keys,
    const float* __restrict__ orig, const float* __restrict__ Rm,
    const float* __restrict__ tv, const float* __restrict__ scale,
    const float* __restrict__ shift, float* __restrict__ tmp)
{
    const int bid   = blockIdx.x;
    const int g     = bid >> 6;
    const int chunk = bid & 63;
    const int b     = g >> 2;
    const int h     = g & 3;

    __shared__ float sc[32], sh[32], sR[9], st3[3], ksc[3], ksh[3];
    const int t = threadIdx.x;
    if (t < 32)      { sc[t] = scale[12 + h * 32 + t]; sh[t] = shift[12 + h * 32 + t]; }
    else if (t < 41) { sR[t - 32]  = Rm[h * 9 + (t - 32)]; }
    else if (t < 44) { st3[t - 41] = tv[h * 3 + (t - 41)]; }
    else if (t < 47) { ksc[t - 44] = scale[h * 3 + (t - 44)];
                       ksh[t - 44] = shift[h * 3 + (t - 44)]; }
    __syncthreads();

    const int f   = t & 31;
    const int grp = t >> 5;
    const float scf = sc[f], shf = sh[f];
    float* const tg = tmp + ((size_t)g << 20);          // g * G3 * F

    const int co[8] = { 0, 1, 32, 33, 1024, 1025, 1056, 1057 };
    const int nbase = (chunk << 8) + (grp << 5);

    for (int i = 0; i < 32; ++i) {
        const int n = nbase + i;

        // all 32 lanes compute point transform redundantly (broadcast loads)
        const float k0 = fmaf(keys[(size_t)(g * 3 + 0) * Nn + n], ksc[0], ksh[0]);
        const float k1 = fmaf(keys[(size_t)(g * 3 + 1) * Nn + n], ksc[1], ksh[1]);
        const float k2 = fmaf(keys[(size_t)(g * 3 + 2) * Nn + n], ksc[2], ksh[2]);
        const float p0 = orig[(size_t)(b * 3 + 0) * Nn + n] + k0;
        const float p1 = orig[(size_t)(b * 3 + 1) * Nn + n] + k1;
        const float p2 = orig[(size_t)(b * 3 + 2) * Nn + n] + k2;

        int   idx[3];
        float loc[3];
        #pragma unroll
        for (int d = 0; d < 3; ++d) {
            const float tk = fmaf(sR[d*3+0], p0, fmaf(sR[d*3+1], p1, fmaf(sR[d*3+2], p2, st3[d])));
            const float la = tanhf(tk);
            const float po = (la + 1.f) * 15.5f;
            float fi = floorf(po);
            fi = fminf(fmaxf(fi, 0.f), 30.f);
            idx[d] = (int)fi;
            loc[d] = po - fi;
        }
        const int cell = (idx[0] * Gg + idx[1]) * Gg + idx[2];

        const float wx1 = loc[0], wx0 = 1.f - loc[0];
        const float wy1 = loc[1], wy0 = 1.f - loc[1];
        const float wz1 = loc[2], wz0 = 1.f - loc[2];
        const float cw[8] = { wx0*wy0*wz0, wx0*wy0*wz1, wx0*wy1*wz0, wx0*wy1*wz1,
                              wx1*wy0*wz0, wx1*wy0*wz1, wx1*wy1*wz0, wx1*wy1*wz1 };

        const float v = fmaf(vals[((size_t)g * Nn + n) * Ff + f], scf, shf);

        #pragma unroll
        for (int c8 = 0; c8 < 8; ++c8) {
            atomicAdd(tg + ((size_t)(cell + co[c8]) << 5) + f, cw[c8] * v);
        }
    }
}

// ---------------- Pass 4: transpose [g][cell][f] -> [g][f][cell] ----------------
// Grid: 32 g x 512 tiles (64 cells each) = 16384 blocks, 256 threads.
__global__ __launch_bounds__(256) void transpose_kernel(
    const float* __restrict__ tmp, float* __restrict__ out)
{
    __shared__ float lds[64][33];
    const int bid  = blockIdx.x;
    const int g    = bid >> 9;
    const int tile = bid & 511;
    const int c0   = tile << 6;
    const int t    = threadIdx.x;

    const float* tg = tmp + ((size_t)g << 20);
    #pragma unroll
    for (int k = 0; k < 8; ++k) {
        const int idx = t + (k << 8);
        const int cl = idx >> 5, f = idx & 31;
        lds[cl][f] = tg[((size_t)(c0 + cl) << 5) + f];
    }
    __syncthreads();
    float* og = out + ((size_t)g << 20);
    #pragma unroll
    for (int k = 0; k < 8; ++k) {
        const int idx = t + (k << 8);
        const int f = idx >> 6, cl = idx & 63;
        og[(size_t)f * G3v + c0 + cl] = lds[cl][f];
    }
}

// ---------------- Fallback: old direct-layout scatter (if ws too small) ----------------
__global__ __launch_bounds__(256) void scatter_kernel(
    const float* __restrict__ vals, const float* __restrict__ keys,
    const float* __restrict__ orig, const float* __restrict__ Rm,
    const float* __restrict__ tv, const float* __restrict__ scale,
    const float* __restrict__ shift, float* __restrict__ out)
{
    const int bid   = blockIdx.x;
    const int g     = bid >> 5;
    const int chunk = bid & 31;
    const int b     = g >> 2;
    const int h     = g & 3;

    __shared__ float sc[32], sh[32], sR[9], st3[3], ksc[3], ksh[3];
    const int t = threadIdx.x;
    if (t < 32)      { sc[t] = scale[12 + h * 32 + t]; sh[t] = shift[12 + h * 32 + t]; }
    else if (t < 41) { sR[t - 32]  = Rm[h * 9 + (t - 32)]; }
    else if (t < 44) { st3[t - 41] = tv[h * 3 + (t - 41)]; }
    else if (t < 47) { ksc[t - 44] = scale[h * 3 + (t - 44)];
                       ksh[t - 44] = shift[h * 3 + (t - 44)]; }
    __syncthreads();

    float* const og = out + ((size_t)g << 20);

    #pragma unroll
    for (int pp = 0; pp < 2; ++pp) {
        const int n = (chunk << 9) + (pp << 8) + t;

        const float k0 = fmaf(keys[(size_t)(g * 3 + 0) * Nn + n], ksc[0], ksh[0]);
        const float k1 = fmaf(keys[(size_t)(g * 3 + 1) * Nn + n], ksc[1], ksh[1]);
        const float k2 = fmaf(keys[(size_t)(g * 3 + 2) * Nn + n], ksc[2], ksh[2]);
        const float p0 = orig[(size_t)(b * 3 + 0) * Nn + n] + k0;
        const float p1 = orig[(size_t)(b * 3 + 1) * Nn + n] + k1;
        const float p2 = orig[(size_t)(b * 3 + 2) * Nn + n] + k2;

        int   idx[3];
        float loc[3];
        #pragma unroll
        for (int d = 0; d < 3; ++d) {
            const float tk = fmaf(sR[d*3+0], p0, fmaf(sR[d*3+1], p1, fmaf(sR[d*3+2], p2, st3[d])));
            const float la = tanhf(tk);
            const float po = (la + 1.f) * 15.5f;
            float fi = floorf(po);
            fi = fminf(fmaxf(fi, 0.f), 30.f);
            idx[d] = (int)fi;
            loc[d] = po - fi;
        }
        const int cell = (idx[0] * Gg + idx[1]) * Gg + idx[2];

        float v[32];
        const float4* vp = reinterpret_cast<const float4*>(vals + ((size_t)g * Nn + n) * Ff);
        #pragma unroll
        for (int q = 0; q < 8; ++q) {
            const float4 x = vp[q];
            v[4*q+0] = fmaf(x.x, sc[4*q+0], sh[4*q+0]);
            v[4*q+1] = fmaf(x.y, sc[4*q+1], sh[4*q+1]);
            v[4*q+2] = fmaf(x.z, sc[4*q+2], sh[4*q+2]);
            v[4*q+3] = fmaf(x.w, sc[4*q+3], sh[4*q+3]);
        }

        const float wx1 = loc[0], wx0 = 1.f - loc[0];
        const float wy1 = loc[1], wy0 = 1.f - loc[1];
        const float wz1 = loc[2], wz0 = 1.f - loc[2];
        const float cw[8] = { wx0*wy0*wz0, wx0*wy0*wz1, wx0*wy1*wz0, wx0*wy1*wz1,
                              wx1*wy0*wz0, wx1*wy0*wz1, wx1*wy1*wz0, wx1*wy1*wz1 };
        const int  co[8] = { 0, 1, 32, 33, 1024, 1025, 1056, 1057 };

        #pragma unroll
        for (int ff = 0; ff < 32; ++ff) {
            float* const pf = og + (size_t)ff * G3v + cell;
            const float vf = v[ff];
            #pragma unroll
            for (int c8 = 0; c8 < 8; ++c8) {
                atomicAdd(pf + co[c8], cw[c8] * vf);
            }
        }
    }
}

extern "C" void kernel_launch(void* const* d_in, const int* in_sizes, int n_in,
                              void* d_out, int out_size, void* d_ws, size_t ws_size,
                              hipStream_t stream)
{
    const float* X    = (const float*)d_in[0];
    const float* orig = (const float*)d_in[1];
    const float* W    = (const float*)d_in[2];
    const float* kg   = (const float*)d_in[3];
    const float* kb   = (const float*)d_in[4];
    const float* vg   = (const float*)d_in[5];
    const float* vb   = (const float*)d_in[6];
    const float* Rm   = (const float*)d_in[7];
    const float* tv   = (const float*)d_in[8];
    float* out = (float*)d_out;
    float* ws  = (float*)d_ws;

    // layout (floats): vals 16,777,216 | keys 1,572,864 | sum/sq/scale/shift 560 | pad | tmp 33,554,432
    float* vals  = ws;
    float* keys  = ws + 16777216;
    float* gsum  = ws + 18350080;
    float* gsq   = gsum + 140;
    float* scale = gsum + 280;
    float* shift = scale + 140;
    float* tmp   = ws + 18874368;   // 72 MiB offset; tmp = 128 MiB
    const size_t need_bytes = (size_t)(18874368 + 33554432) * sizeof(float); // 200 MiB

    hipMemsetAsync(gsum, 0, 280 * sizeof(float), stream);

    gemm_stats_kernel<<<2048, 256, 0, stream>>>(X, W, vals, keys, gsum, gsq);
    finalize_kernel<<<1, 256, 0, stream>>>(gsum, gsq, kg, kb, vg, vb, scale, shift);

    if (ws_size >= need_bytes) {
        hipMemsetAsync(tmp, 0, (size_t)33554432 * sizeof(float), stream);
        scatter_cf_kernel<<<2048, 256, 0, stream>>>(vals, keys, orig, Rm, tv, scale, shift, tmp);
        transpose_kernel<<<16384, 256, 0, stream>>>(tmp, out);
    } else {
        hipMemsetAsync(out, 0, (size_t)out_size * sizeof(float), stream);
        scatter_kernel<<<1024, 256, 0, stream>>>(vals, keys, orig, Rm, tv, scale, shift, out);
    }
}